// Round 1
// baseline (422.960 us; speedup 1.0000x reference)
//
#include <hip/hip_runtime.h>

#define HH 512
#define WW 512
#define PLANES 96          // 32 * 3
#define RSTRIP 66          // output rows per block (6 * 11 for static phase indexing)
#define NPIX 25165824.0f   // 32*3*512*512

// Gaussian weights (sigma=1.5, K=11), symmetric: G[k] for |offset|=k
#define G0 0.2660117f
#define G1 0.2130056f
#define G2 0.1093607f
#define G3 0.0360008f
#define G4 0.0075988f
#define G5 0.0010284f

#define C1F 1e-4f
#define C2F 9e-4f

// Horizontal 11-tap conv of the 5 quantities {x, y, x^2, y^2, x*y} for one row,
// one column per lane. r1/r2 point at (row, c); tap k reads offset k-5.
template <bool GUARD>
__device__ __forceinline__ void hconv(const float* __restrict__ r1,
                                      const float* __restrict__ r2,
                                      int c, float h[5]) {
    float x[11], y[11];
#pragma unroll
    for (int k = 0; k < 11; ++k) {
        if (GUARD) {
            int cc = c + k - 5;
            bool ok = (unsigned)cc < (unsigned)WW;
            x[k] = ok ? r1[k - 5] : 0.f;
            y[k] = ok ? r2[k - 5] : 0.f;
        } else {
            x[k] = r1[k - 5];
            y[k] = r2[k - 5];
        }
    }
    float hx  = G0 * x[5];
    float hy  = G0 * y[5];
    float hx2 = G0 * (x[5] * x[5]);
    float hy2 = G0 * (y[5] * y[5]);
    float hxy = G0 * (x[5] * y[5]);
    const float gk[5] = {G1, G2, G3, G4, G5};
#pragma unroll
    for (int k = 1; k <= 5; ++k) {
        float xa = x[5 - k], xb = x[5 + k];
        float ya = y[5 - k], yb = y[5 + k];
        float g = gk[k - 1];
        hx  = fmaf(g, xa + xb, hx);
        hy  = fmaf(g, ya + yb, hy);
        hx2 = fmaf(g, fmaf(xa, xa, xb * xb), hx2);
        hy2 = fmaf(g, fmaf(ya, ya, yb * yb), hy2);
        hxy = fmaf(g, fmaf(xa, ya, xb * yb), hxy);
    }
    h[0] = hx; h[1] = hy; h[2] = hx2; h[3] = hy2; h[4] = hxy;
}

__global__ __launch_bounds__(256) void ssim_main(const float* __restrict__ img1,
                                                 const float* __restrict__ img2,
                                                 float* __restrict__ acc) {
    const int c  = blockIdx.x * 256 + threadIdx.x;   // column (0..511)
    const int r0 = blockIdx.y * RSTRIP;              // first output row of strip
    const int p  = blockIdx.z;                       // plane (b*3+ch)
    const size_t pb = (size_t)p * (HH * WW);
    const float* b1 = img1 + pb + c;
    const float* b2 = img2 + pb + c;
    const bool edge = (c < 5) || (c > WW - 6);

    // circular history of horizontally-convolved rows: hist[q][slot], slot = (t-(r0-5)) mod 11
    float hist[5][11];

    // warm-up: rows t = r0-5 .. r0+4 -> slots 0..9
#pragma unroll
    for (int w = 0; w < 10; ++w) {
        const int t = r0 - 5 + w;
        float h[5] = {0.f, 0.f, 0.f, 0.f, 0.f};
        if ((unsigned)t < (unsigned)HH) {
            const float* r1 = b1 + (size_t)t * WW;
            const float* r2 = b2 + (size_t)t * WW;
            if (edge) hconv<true>(r1, r2, c, h);
            else      hconv<false>(r1, r2, c, h);
        }
#pragma unroll
        for (int q = 0; q < 5; ++q) hist[q][w] = h[q];
    }

    float lsum = 0.f;
#pragma unroll 1
    for (int sb = 0; sb < RSTRIP; sb += 11) {
#pragma unroll
        for (int ph = 0; ph < 11; ++ph) {
            const int s = sb + ph;
            const int t = r0 + 5 + s;             // new input row
            const int slot = (ph + 10) % 11;      // static after unroll
            float h[5] = {0.f, 0.f, 0.f, 0.f, 0.f};
            if (t < HH) {                          // uniform branch (t >= 5 always here)
                const float* r1 = b1 + (size_t)t * WW;
                const float* r2 = b2 + (size_t)t * WW;
                if (edge) hconv<true>(r1, r2, c, h);
                else      hconv<false>(r1, r2, c, h);
            }
#pragma unroll
            for (int q = 0; q < 5; ++q) hist[q][slot] = h[q];

            const int o = r0 + s;                 // completed output row
            if (o < HH) {
                float v[5];
#pragma unroll
                for (int q = 0; q < 5; ++q) {
                    // vertical 11-tap: row o+k lives in slot (ph+5+k) mod 11 (static)
                    float vv = G0 * hist[q][(ph + 5) % 11];
                    vv = fmaf(G1, hist[q][(ph + 4) % 11] + hist[q][(ph + 6) % 11], vv);
                    vv = fmaf(G2, hist[q][(ph + 3) % 11] + hist[q][(ph + 7) % 11], vv);
                    vv = fmaf(G3, hist[q][(ph + 2) % 11] + hist[q][(ph + 8) % 11], vv);
                    vv = fmaf(G4, hist[q][(ph + 1) % 11] + hist[q][(ph + 9) % 11], vv);
                    vv = fmaf(G5, hist[q][(ph + 0) % 11] + hist[q][(ph + 10) % 11], vv);
                    v[q] = vv;
                }
                const float mu1 = v[0], mu2 = v[1];
                const float mu1sq = mu1 * mu1;
                const float mu2sq = mu2 * mu2;
                const float mu12  = mu1 * mu2;
                const float s1  = v[2] - mu1sq;
                const float s2  = v[3] - mu2sq;
                const float s12 = v[4] - mu12;
                const float num = fmaf(2.f, mu12, C1F) * fmaf(2.f, s12, C2F);
                const float den = (mu1sq + mu2sq + C1F) * (s1 + s2 + C2F);
                lsum += num * __builtin_amdgcn_rcpf(den);
            }
        }
    }

    // reduction: wave shfl -> LDS -> one atomic per block
#pragma unroll
    for (int off = 32; off > 0; off >>= 1)
        lsum += __shfl_down(lsum, off, 64);
    __shared__ float ws4[4];
    const int lane = threadIdx.x & 63;
    const int wv   = threadIdx.x >> 6;
    if (lane == 0) ws4[wv] = lsum;
    __syncthreads();
    if (threadIdx.x == 0)
        atomicAdd(acc, ws4[0] + ws4[1] + ws4[2] + ws4[3]);
}

__global__ void ssim_zero(float* acc) { acc[0] = 0.f; }

__global__ void ssim_finalize(const float* __restrict__ acc, float* __restrict__ out) {
    out[0] = 1.f - acc[0] * (1.f / NPIX);
}

extern "C" void kernel_launch(void* const* d_in, const int* in_sizes, int n_in,
                              void* d_out, int out_size, void* d_ws, size_t ws_size,
                              hipStream_t stream) {
    const float* img1 = (const float*)d_in[0];
    const float* img2 = (const float*)d_in[1];
    float* out = (float*)d_out;
    float* acc = (float*)d_ws;

    ssim_zero<<<1, 1, 0, stream>>>(acc);
    dim3 grid(WW / 256, (HH + RSTRIP - 1) / RSTRIP, PLANES);  // (2, 8, 96)
    ssim_main<<<grid, 256, 0, stream>>>(img1, img2, acc);
    ssim_finalize<<<1, 1, 0, stream>>>(acc, out);
}

// Round 2
// 421.998 us; speedup vs baseline: 1.0023x; 1.0023x over previous
//
#include <hip/hip_runtime.h>

#define HH 512
#define WW 512
#define PLANES 96          // 32 * 3
#define RSTRIP 66          // output rows per block (6 * 11 for static phase indexing)
#define NPIX 25165824.0f   // 32*3*512*512

// Gaussian weights (sigma=1.5, K=11), symmetric: G[k] for |offset|=k
#define G0 0.2660117f
#define G1 0.2130056f
#define G2 0.1093607f
#define G3 0.0360008f
#define G4 0.0075988f
#define G5 0.0010284f

#define C1F 1e-4f
#define C2F 9e-4f

// Horizontal 11-tap conv of the 5 quantities {x, y, x^2, y^2, x*y} for one row,
// one column per lane. r1/r2 point at (row, c); tap k reads offset k-5.
template <bool GUARD>
__device__ __forceinline__ void hconv(const float* __restrict__ r1,
                                      const float* __restrict__ r2,
                                      int c, float h[5]) {
    float x[11], y[11];
#pragma unroll
    for (int k = 0; k < 11; ++k) {
        if (GUARD) {
            int cc = c + k - 5;
            bool ok = (unsigned)cc < (unsigned)WW;
            x[k] = ok ? r1[k - 5] : 0.f;
            y[k] = ok ? r2[k - 5] : 0.f;
        } else {
            x[k] = r1[k - 5];
            y[k] = r2[k - 5];
        }
    }
    float hx  = G0 * x[5];
    float hy  = G0 * y[5];
    float hx2 = G0 * (x[5] * x[5]);
    float hy2 = G0 * (y[5] * y[5]);
    float hxy = G0 * (x[5] * y[5]);
    const float gk[5] = {G1, G2, G3, G4, G5};
#pragma unroll
    for (int k = 1; k <= 5; ++k) {
        float xa = x[5 - k], xb = x[5 + k];
        float ya = y[5 - k], yb = y[5 + k];
        float g = gk[k - 1];
        hx  = fmaf(g, xa + xb, hx);
        hy  = fmaf(g, ya + yb, hy);
        hx2 = fmaf(g, fmaf(xa, xa, xb * xb), hx2);
        hy2 = fmaf(g, fmaf(ya, ya, yb * yb), hy2);
        hxy = fmaf(g, fmaf(xa, ya, xb * yb), hxy);
    }
    h[0] = hx; h[1] = hy; h[2] = hx2; h[3] = hy2; h[4] = hxy;
}

// launch_bounds(256, 3): min 3 waves/EU -> VGPR cap ~170. The register
// circular buffer hist[5][11] (55 floats) + 22 tap temps needs ~110 live
// VGPRs; the default occupancy-greedy budget (64) spilled it to scratch
// (round 1: VGPR_Count=48, 292us, VALUBusy 35%).
__global__ __launch_bounds__(256, 3) void ssim_main(const float* __restrict__ img1,
                                                    const float* __restrict__ img2,
                                                    float* __restrict__ acc) {
    const int c  = blockIdx.x * 256 + threadIdx.x;   // column (0..511)
    const int r0 = blockIdx.y * RSTRIP;              // first output row of strip
    const int p  = blockIdx.z;                       // plane (b*3+ch)
    const size_t pb = (size_t)p * (HH * WW);
    const float* b1 = img1 + pb + c;
    const float* b2 = img2 + pb + c;
    const bool edge = (c < 5) || (c > WW - 6);

    // circular history of horizontally-convolved rows: hist[q][slot], slot = (t-(r0-5)) mod 11
    float hist[5][11];

    // warm-up: rows t = r0-5 .. r0+4 -> slots 0..9
#pragma unroll
    for (int w = 0; w < 10; ++w) {
        const int t = r0 - 5 + w;
        float h[5] = {0.f, 0.f, 0.f, 0.f, 0.f};
        if ((unsigned)t < (unsigned)HH) {
            const float* r1 = b1 + (size_t)t * WW;
            const float* r2 = b2 + (size_t)t * WW;
            if (edge) hconv<true>(r1, r2, c, h);
            else      hconv<false>(r1, r2, c, h);
        }
#pragma unroll
        for (int q = 0; q < 5; ++q) hist[q][w] = h[q];
    }

    float lsum = 0.f;
#pragma unroll 1
    for (int sb = 0; sb < RSTRIP; sb += 11) {
#pragma unroll
        for (int ph = 0; ph < 11; ++ph) {
            const int s = sb + ph;
            const int t = r0 + 5 + s;             // new input row
            const int slot = (ph + 10) % 11;      // static after unroll
            float h[5] = {0.f, 0.f, 0.f, 0.f, 0.f};
            if (t < HH) {                          // uniform branch (t >= 5 always here)
                const float* r1 = b1 + (size_t)t * WW;
                const float* r2 = b2 + (size_t)t * WW;
                if (edge) hconv<true>(r1, r2, c, h);
                else      hconv<false>(r1, r2, c, h);
            }
#pragma unroll
            for (int q = 0; q < 5; ++q) hist[q][slot] = h[q];

            const int o = r0 + s;                 // completed output row
            if (o < HH) {
                float v[5];
#pragma unroll
                for (int q = 0; q < 5; ++q) {
                    // vertical 11-tap: row o+k lives in slot (ph+5+k) mod 11 (static)
                    float vv = G0 * hist[q][(ph + 5) % 11];
                    vv = fmaf(G1, hist[q][(ph + 4) % 11] + hist[q][(ph + 6) % 11], vv);
                    vv = fmaf(G2, hist[q][(ph + 3) % 11] + hist[q][(ph + 7) % 11], vv);
                    vv = fmaf(G3, hist[q][(ph + 2) % 11] + hist[q][(ph + 8) % 11], vv);
                    vv = fmaf(G4, hist[q][(ph + 1) % 11] + hist[q][(ph + 9) % 11], vv);
                    vv = fmaf(G5, hist[q][(ph + 0) % 11] + hist[q][(ph + 10) % 11], vv);
                    v[q] = vv;
                }
                const float mu1 = v[0], mu2 = v[1];
                const float mu1sq = mu1 * mu1;
                const float mu2sq = mu2 * mu2;
                const float mu12  = mu1 * mu2;
                const float s1  = v[2] - mu1sq;
                const float s2  = v[3] - mu2sq;
                const float s12 = v[4] - mu12;
                const float num = fmaf(2.f, mu12, C1F) * fmaf(2.f, s12, C2F);
                const float den = (mu1sq + mu2sq + C1F) * (s1 + s2 + C2F);
                lsum += num * __builtin_amdgcn_rcpf(den);
            }
        }
    }

    // reduction: wave shfl -> LDS -> one atomic per block
#pragma unroll
    for (int off = 32; off > 0; off >>= 1)
        lsum += __shfl_down(lsum, off, 64);
    __shared__ float ws4[4];
    const int lane = threadIdx.x & 63;
    const int wv   = threadIdx.x >> 6;
    if (lane == 0) ws4[wv] = lsum;
    __syncthreads();
    if (threadIdx.x == 0)
        atomicAdd(acc, ws4[0] + ws4[1] + ws4[2] + ws4[3]);
}

__global__ void ssim_zero(float* acc) { acc[0] = 0.f; }

__global__ void ssim_finalize(const float* __restrict__ acc, float* __restrict__ out) {
    out[0] = 1.f - acc[0] * (1.f / NPIX);
}

extern "C" void kernel_launch(void* const* d_in, const int* in_sizes, int n_in,
                              void* d_out, int out_size, void* d_ws, size_t ws_size,
                              hipStream_t stream) {
    const float* img1 = (const float*)d_in[0];
    const float* img2 = (const float*)d_in[1];
    float* out = (float*)d_out;
    float* acc = (float*)d_ws;

    ssim_zero<<<1, 1, 0, stream>>>(acc);
    dim3 grid(WW / 256, (HH + RSTRIP - 1) / RSTRIP, PLANES);  // (2, 8, 96)
    ssim_main<<<grid, 256, 0, stream>>>(img1, img2, acc);
    ssim_finalize<<<1, 1, 0, stream>>>(acc, out);
}

// Round 3
// 420.715 us; speedup vs baseline: 1.0053x; 1.0030x over previous
//
#include <hip/hip_runtime.h>

#define HH 512
#define WW 512
#define PLANES 96          // 32 * 3
#define RSTRIP 64          // output rows per block
#define NPIX 25165824.0f   // 32*3*512*512

// Gaussian weights (sigma=1.5, K=11), symmetric: G[k] for |offset|=k
#define G0 0.2660117f
#define G1 0.2130056f
#define G2 0.1093607f
#define G3 0.0360008f
#define G4 0.0075988f
#define G5 0.0010284f

#define C1F 1e-4f
#define C2F 9e-4f

// Horizontal 11-tap conv of the 5 quantities {x, y, x^2, y^2, x*y} for one row,
// one column per lane. r1/r2 point at (row, c); tap k reads offset k-5.
template <bool GUARD>
__device__ __forceinline__ void hconv(const float* __restrict__ r1,
                                      const float* __restrict__ r2,
                                      int c, float h[5]) {
    float x[11], y[11];
#pragma unroll
    for (int k = 0; k < 11; ++k) {
        if (GUARD) {
            int cc = c + k - 5;
            bool ok = (unsigned)cc < (unsigned)WW;
            x[k] = ok ? r1[k - 5] : 0.f;
            y[k] = ok ? r2[k - 5] : 0.f;
        } else {
            x[k] = r1[k - 5];
            y[k] = r2[k - 5];
        }
    }
    float hx  = G0 * x[5];
    float hy  = G0 * y[5];
    float hx2 = G0 * (x[5] * x[5]);
    float hy2 = G0 * (y[5] * y[5]);
    float hxy = G0 * (x[5] * y[5]);
    const float gk[5] = {G1, G2, G3, G4, G5};
#pragma unroll
    for (int k = 1; k <= 5; ++k) {
        float xa = x[5 - k], xb = x[5 + k];
        float ya = y[5 - k], yb = y[5 + k];
        float g = gk[k - 1];
        hx  = fmaf(g, xa + xb, hx);
        hy  = fmaf(g, ya + yb, hy);
        hx2 = fmaf(g, fmaf(xa, xa, xb * xb), hx2);
        hy2 = fmaf(g, fmaf(ya, ya, yb * yb), hy2);
        hxy = fmaf(g, fmaf(xa, ya, xb * yb), hxy);
    }
    h[0] = hx; h[1] = hy; h[2] = hx2; h[3] = hy2; h[4] = hxy;
}

// History is an explicit SHIFT REGISTER: every access uses a literal constant
// index; the per-row shift is a pair of tiny fully-unrolled loops. Rounds 1-2
// showed the circular-buffer version ((ph+k)%11 indices, needed a huge 11-phase
// unroll to become constant) was never SROA-promoted: VGPR_Count=52 < 55 live
// floats -> hist sat in scratch -> ~7 GB of L2/L3 scratch traffic, 283us,
// VALUBusy 35%. Constant indices make promotion unconditional.
// launch_bounds(256,3): VGPR cap ~170 for the ~110 live regs (55 hist + taps).
__global__ __launch_bounds__(256, 3) void ssim_main(const float* __restrict__ img1,
                                                    const float* __restrict__ img2,
                                                    float* __restrict__ acc) {
    const int c  = blockIdx.x * 256 + threadIdx.x;   // column (0..511)
    const int r0 = blockIdx.y * RSTRIP;              // first output row of strip
    const int p  = blockIdx.z;                       // plane (b*3+ch)
    const size_t pb = (size_t)p * (HH * WW);
    const float* b1 = img1 + pb + c;
    const float* b2 = img2 + pb + c;
    const bool edge = (c < 5) || (c > WW - 6);

    float hist[5][11];
#pragma unroll
    for (int q = 0; q < 5; ++q)
#pragma unroll
        for (int i = 0; i < 11; ++i) hist[q][i] = 0.f;

    float lsum = 0.f;

    // Single pass over input rows t = r0-5 .. r0+RSTRIP+4 (74 iters).
    // After processing row t, hist[q][10-j] holds h_q(row t-j); output row
    // o = t-5 is complete once t >= r0+5 (the first 10 iters are warm-up).
#pragma unroll 2
    for (int t = r0 - 5; t <= r0 + RSTRIP + 4; ++t) {
        // shift out the oldest row (constant indices -> pure register renames)
#pragma unroll
        for (int q = 0; q < 5; ++q)
#pragma unroll
            for (int i = 0; i < 10; ++i) hist[q][i] = hist[q][i + 1];

        float h[5] = {0.f, 0.f, 0.f, 0.f, 0.f};
        if ((unsigned)t < (unsigned)HH) {            // uniform; zero-pad rows outside
            const float* r1 = b1 + (size_t)t * WW;
            const float* r2 = b2 + (size_t)t * WW;
            if (edge) hconv<true>(r1, r2, c, h);
            else      hconv<false>(r1, r2, c, h);
        }
#pragma unroll
        for (int q = 0; q < 5; ++q) hist[q][10] = h[q];

        const int s = t - 5 - r0;                    // output row within strip
        if ((unsigned)s < (unsigned)RSTRIP) {        // uniform
            float v[5];
#pragma unroll
            for (int q = 0; q < 5; ++q) {
                float vv = G0 * hist[q][5];
                vv = fmaf(G1, hist[q][4] + hist[q][6], vv);
                vv = fmaf(G2, hist[q][3] + hist[q][7], vv);
                vv = fmaf(G3, hist[q][2] + hist[q][8], vv);
                vv = fmaf(G4, hist[q][1] + hist[q][9], vv);
                vv = fmaf(G5, hist[q][0] + hist[q][10], vv);
                v[q] = vv;
            }
            const float mu1 = v[0], mu2 = v[1];
            const float mu1sq = mu1 * mu1;
            const float mu2sq = mu2 * mu2;
            const float mu12  = mu1 * mu2;
            const float s1  = v[2] - mu1sq;
            const float s2  = v[3] - mu2sq;
            const float s12 = v[4] - mu12;
            const float num = fmaf(2.f, mu12, C1F) * fmaf(2.f, s12, C2F);
            const float den = (mu1sq + mu2sq + C1F) * (s1 + s2 + C2F);
            lsum += num * __builtin_amdgcn_rcpf(den);
        }
    }

    // reduction: wave shfl -> LDS -> one atomic per block
#pragma unroll
    for (int off = 32; off > 0; off >>= 1)
        lsum += __shfl_down(lsum, off, 64);
    __shared__ float ws4[4];
    const int lane = threadIdx.x & 63;
    const int wv   = threadIdx.x >> 6;
    if (lane == 0) ws4[wv] = lsum;
    __syncthreads();
    if (threadIdx.x == 0)
        atomicAdd(acc, ws4[0] + ws4[1] + ws4[2] + ws4[3]);
}

__global__ void ssim_zero(float* acc) { acc[0] = 0.f; }

__global__ void ssim_finalize(const float* __restrict__ acc, float* __restrict__ out) {
    out[0] = 1.f - acc[0] * (1.f / NPIX);
}

extern "C" void kernel_launch(void* const* d_in, const int* in_sizes, int n_in,
                              void* d_out, int out_size, void* d_ws, size_t ws_size,
                              hipStream_t stream) {
    const float* img1 = (const float*)d_in[0];
    const float* img2 = (const float*)d_in[1];
    float* out = (float*)d_out;
    float* acc = (float*)d_ws;

    ssim_zero<<<1, 1, 0, stream>>>(acc);
    dim3 grid(WW / 256, HH / RSTRIP, PLANES);  // (2, 8, 96)
    ssim_main<<<grid, 256, 0, stream>>>(img1, img2, acc);
    ssim_finalize<<<1, 1, 0, stream>>>(acc, out);
}

// Round 4
// 402.059 us; speedup vs baseline: 1.0520x; 1.0464x over previous
//
#include <hip/hip_runtime.h>

#define HH 512
#define WW 512
#define PLANES 96          // 32 * 3
#define RSTRIP 128         // output rows per block; halo overhead (RSTRIP+10)/RSTRIP = 7.8%
#define NPIX 25165824.0f   // 32*3*512*512

// Gaussian weights (sigma=1.5, K=11), symmetric; these exact constants gave absmax 0.0
#define G0 0.2660117f
#define G1 0.2130056f
#define G2 0.1093607f
#define G3 0.0360008f
#define G4 0.0075988f
#define G5 0.0010284f

#define C1F 1e-4f
#define C2F 9e-4f

// 4-float unaligned load helper (4B-aligned dwordx4 is legal on gfx950)
struct F4 { float s0, s1, s2, s3; };

// ---- named-scalar 11-deep history (NO ARRAYS: rounds 1-3 proved C arrays with
// loop-carried lifetime never get SROA-promoted here -> scratch-resident ->
// ~7 GB scratch traffic, occupancy capped at 12 waves/CU by scratch backing,
// 290us. Named scalars are SSA values; scratch is impossible without RA spill.)
#define DECL_HIST(Z) float Z##0=0.f,Z##1=0.f,Z##2=0.f,Z##3=0.f,Z##4=0.f,Z##5=0.f,\
                           Z##6=0.f,Z##7=0.f,Z##8=0.f,Z##9=0.f,Z##10=0.f
#define SHIFT_HIST(Z) do{Z##0=Z##1;Z##1=Z##2;Z##2=Z##3;Z##3=Z##4;Z##4=Z##5;\
                         Z##5=Z##6;Z##6=Z##7;Z##7=Z##8;Z##8=Z##9;Z##9=Z##10;}while(0)
#define VCONV(Z) fmaf(G5, Z##0+Z##10, fmaf(G4, Z##1+Z##9, fmaf(G3, Z##2+Z##8,\
                 fmaf(G2, Z##3+Z##7, fmaf(G1, Z##4+Z##6, G0*Z##5)))))

__global__ __launch_bounds__(256, 3) void ssim_main(const float* __restrict__ img1,
                                                    const float* __restrict__ img2,
                                                    float* __restrict__ acc) {
    const int c  = blockIdx.x * 256 + threadIdx.x;   // column (0..511)
    const int r0 = blockIdx.y * RSTRIP;              // first output row of strip
    const int p  = blockIdx.z;                       // plane (b*3+ch)
    const size_t pb = (size_t)p * (HH * WW);
    // lanes that cannot use the 12-wide vector load (need c-5 >= 0, c+6 <= 511)
    const bool edge = (c < 5) || (c > WW - 7);

    // row pointers at (t, c); advanced by WW per iteration (deref is guarded)
    const float* rp1 = img1 + pb + (ptrdiff_t)(r0 - 5) * WW + c;
    const float* rp2 = img2 + pb + (ptrdiff_t)(r0 - 5) * WW + c;

    // histories: A=conv(u), B=conv(v), P=conv(u^2), Q=conv(v^2); u=x+y, v=x-y.
    // SSIM needs only mu1^2+mu2^2, mu1*mu2, conv(x^2)+conv(y^2), conv(xy) —
    // all recoverable from these 4 (saves a 5th convolution + 11 history regs).
    DECL_HIST(A); DECL_HIST(B); DECL_HIST(P); DECL_HIST(Q);

    float lsum = 0.f;

#pragma unroll 2
    for (int t = r0 - 5; t <= r0 + RSTRIP + 4; ++t, rp1 += WW, rp2 += WW) {
        SHIFT_HIST(A); SHIFT_HIST(B); SHIFT_HIST(P); SHIFT_HIST(Q);

        float nA = 0.f, nB = 0.f, nP = 0.f, nQ = 0.f;
        if ((unsigned)t < (unsigned)HH) {            // uniform; rows outside are zero-pad
            float X0,X1,X2,X3,X4,X5,X6,X7,X8,X9,X10;
            float Y0,Y1,Y2,Y3,Y4,Y5,Y6,Y7,Y8,Y9,Y10;
            if (!edge) {
                F4 xa, xb, xc, ya, yb, yc;
                __builtin_memcpy(&xa, rp1 - 5, 16);
                __builtin_memcpy(&xb, rp1 - 1, 16);
                __builtin_memcpy(&xc, rp1 + 3, 16);
                __builtin_memcpy(&ya, rp2 - 5, 16);
                __builtin_memcpy(&yb, rp2 - 1, 16);
                __builtin_memcpy(&yc, rp2 + 3, 16);
                X0=xa.s0; X1=xa.s1; X2=xa.s2; X3=xa.s3;
                X4=xb.s0; X5=xb.s1; X6=xb.s2; X7=xb.s3;
                X8=xc.s0; X9=xc.s1; X10=xc.s2;
                Y0=ya.s0; Y1=ya.s1; Y2=ya.s2; Y3=ya.s3;
                Y4=yb.s0; Y5=yb.s1; Y6=yb.s2; Y7=yb.s3;
                Y8=yc.s0; Y9=yc.s1; Y10=yc.s2;
            } else {
#define EDGE_TAP(K) { int cc = c + (K) - 5; bool ok = (unsigned)cc < (unsigned)WW; \
                      X##K = ok ? rp1[(K) - 5] : 0.f; Y##K = ok ? rp2[(K) - 5] : 0.f; }
                EDGE_TAP(0) EDGE_TAP(1) EDGE_TAP(2) EDGE_TAP(3) EDGE_TAP(4)
                EDGE_TAP(5) EDGE_TAP(6) EDGE_TAP(7) EDGE_TAP(8) EDGE_TAP(9) EDGE_TAP(10)
#undef EDGE_TAP
            }
            const float U0=X0+Y0, V0=X0-Y0;
            const float U1=X1+Y1, V1=X1-Y1;
            const float U2=X2+Y2, V2=X2-Y2;
            const float U3=X3+Y3, V3=X3-Y3;
            const float U4=X4+Y4, V4=X4-Y4;
            const float U5=X5+Y5, V5=X5-Y5;
            const float U6=X6+Y6, V6=X6-Y6;
            const float U7=X7+Y7, V7=X7-Y7;
            const float U8=X8+Y8, V8=X8-Y8;
            const float U9=X9+Y9, V9=X9-Y9;
            const float U10=X10+Y10, V10=X10-Y10;

            nA = G0*U5;        nB = G0*V5;
            nP = G0*(U5*U5);   nQ = G0*(V5*V5);
            nA = fmaf(G1, U4+U6,  nA); nP = fmaf(G1, fmaf(U4,U4,U6*U6),   nP);
            nB = fmaf(G1, V4+V6,  nB); nQ = fmaf(G1, fmaf(V4,V4,V6*V6),   nQ);
            nA = fmaf(G2, U3+U7,  nA); nP = fmaf(G2, fmaf(U3,U3,U7*U7),   nP);
            nB = fmaf(G2, V3+V7,  nB); nQ = fmaf(G2, fmaf(V3,V3,V7*V7),   nQ);
            nA = fmaf(G3, U2+U8,  nA); nP = fmaf(G3, fmaf(U2,U2,U8*U8),   nP);
            nB = fmaf(G3, V2+V8,  nB); nQ = fmaf(G3, fmaf(V2,V2,V8*V8),   nQ);
            nA = fmaf(G4, U1+U9,  nA); nP = fmaf(G4, fmaf(U1,U1,U9*U9),   nP);
            nB = fmaf(G4, V1+V9,  nB); nQ = fmaf(G4, fmaf(V1,V1,V9*V9),   nQ);
            nA = fmaf(G5, U0+U10, nA); nP = fmaf(G5, fmaf(U0,U0,U10*U10), nP);
            nB = fmaf(G5, V0+V10, nB); nQ = fmaf(G5, fmaf(V0,V0,V10*V10), nQ);
        }
        A10 = nA; B10 = nB; P10 = nP; Q10 = nQ;

        const int s = t - 5 - r0;                    // output row within strip
        if ((unsigned)s < (unsigned)RSTRIP) {        // uniform; first 10 iters warm up
            const float mu_u = VCONV(A);
            const float mu_v = VCONV(B);
            const float cu2  = VCONV(P);
            const float cv2  = VCONV(Q);
            const float a = mu_u * mu_u;
            const float b = mu_v * mu_v;
            const float musq = 0.5f  * (a + b);      // mu1^2 + mu2^2
            const float mu12 = 0.25f * (a - b);      // mu1 * mu2
            const float csq  = 0.5f  * (cu2 + cv2);  // conv(x^2) + conv(y^2)
            const float cxy  = 0.25f * (cu2 - cv2);  // conv(x*y)
            const float ssum = csq - musq;           // sigma1^2 + sigma2^2
            const float s12  = cxy - mu12;           // sigma12
            const float num = fmaf(2.f, mu12, C1F) * fmaf(2.f, s12, C2F);
            const float den = (musq + C1F) * (ssum + C2F);
            lsum += num * __builtin_amdgcn_rcpf(den);
        }
    }

    // reduction: wave shfl -> LDS -> one atomic per block
#pragma unroll
    for (int off = 32; off > 0; off >>= 1)
        lsum += __shfl_down(lsum, off, 64);
    __shared__ float ws4[4];
    const int lane = threadIdx.x & 63;
    const int wv   = threadIdx.x >> 6;
    if (lane == 0) ws4[wv] = lsum;
    __syncthreads();
    if (threadIdx.x == 0)
        atomicAdd(acc, ws4[0] + ws4[1] + ws4[2] + ws4[3]);
}

__global__ void ssim_zero(float* acc) { acc[0] = 0.f; }

__global__ void ssim_finalize(const float* __restrict__ acc, float* __restrict__ out) {
    out[0] = 1.f - acc[0] * (1.f / NPIX);
}

extern "C" void kernel_launch(void* const* d_in, const int* in_sizes, int n_in,
                              void* d_out, int out_size, void* d_ws, size_t ws_size,
                              hipStream_t stream) {
    const float* img1 = (const float*)d_in[0];
    const float* img2 = (const float*)d_in[1];
    float* out = (float*)d_out;
    float* acc = (float*)d_ws;

    ssim_zero<<<1, 1, 0, stream>>>(acc);
    dim3 grid(WW / 256, HH / RSTRIP, PLANES);  // (2, 4, 96) = 768 blocks = 3/CU
    ssim_main<<<grid, 256, 0, stream>>>(img1, img2, acc);
    ssim_finalize<<<1, 1, 0, stream>>>(acc, out);
}

// Round 5
// 397.854 us; speedup vs baseline: 1.0631x; 1.0106x over previous
//
#include <hip/hip_runtime.h>

#define HH 512
#define WW 512
#define PLANES 96          // 32 * 3
#define RSTRIP 128         // output rows per block; halo overhead (RSTRIP+10)/RSTRIP = 7.8%
#define NPIX 25165824.0f   // 32*3*512*512

// Gaussian weights (sigma=1.5, K=11), symmetric; these exact constants gave absmax 0.0
#define G0 0.2660117f
#define G1 0.2130056f
#define G2 0.1093607f
#define G3 0.0360008f
#define G4 0.0075988f
#define G5 0.0010284f

#define C1F 1e-4f
#define C2F 9e-4f

// 4-float unaligned load helper (4B-aligned dwordx4 is legal on gfx950)
struct F4 { float s0, s1, s2, s3; };

// 11-deep named-scalar history (SSA values; no alloca possible)
#define DECL_HIST(Z) float Z##0=0.f,Z##1=0.f,Z##2=0.f,Z##3=0.f,Z##4=0.f,Z##5=0.f,\
                           Z##6=0.f,Z##7=0.f,Z##8=0.f,Z##9=0.f,Z##10=0.f
#define SHIFT_HIST(Z) do{Z##0=Z##1;Z##1=Z##2;Z##2=Z##3;Z##3=Z##4;Z##4=Z##5;\
                         Z##5=Z##6;Z##6=Z##7;Z##7=Z##8;Z##8=Z##9;Z##9=Z##10;}while(0)
#define VCONV(Z) fmaf(G5, Z##0+Z##10, fmaf(G4, Z##1+Z##9, fmaf(G3, Z##2+Z##8,\
                 fmaf(G2, Z##3+Z##7, fmaf(G1, Z##4+Z##6, G0*Z##5)))))

// amdgpu_waves_per_eu(3,3): rounds 1-4 showed the machine scheduler targets the
// MAX of the waves-per-eu range (default ~10 -> ~48-VGPR schedule: VGPR_Count
// 40-52 every round, no scratch traffic [WRITE_SIZE=24KB], loads serialized ->
// ~4700 cyc/block-row-iter, VALUBusy 35%). __launch_bounds__'s 2nd arg only
// raises the MIN. Pinning max=3 (budget ~170 VGPRs) lets the 44-float history
// + 12 hoisted load dests live in registers; grid is exactly 3 blocks/CU so no
// occupancy is actually sacrificed.
__global__ __launch_bounds__(256) __attribute__((amdgpu_waves_per_eu(3, 3)))
void ssim_main(const float* __restrict__ img1,
               const float* __restrict__ img2,
               float* __restrict__ acc) {
    const int c  = blockIdx.x * 256 + threadIdx.x;   // column (0..511)
    const int r0 = blockIdx.y * RSTRIP;              // first output row of strip
    const int p  = blockIdx.z;                       // plane (b*3+ch)
    const size_t pb = (size_t)p * (HH * WW);
    // lanes that cannot use the 12-wide vector load (need c-5 >= 0, c+6 <= 511)
    const bool edge = (c < 5) || (c > WW - 7);

    // row pointers at (t, c); advanced by WW per iteration (deref is guarded)
    const float* rp1 = img1 + pb + (ptrdiff_t)(r0 - 5) * WW + c;
    const float* rp2 = img2 + pb + (ptrdiff_t)(r0 - 5) * WW + c;

    // histories: A=conv(u), B=conv(v), P=conv(u^2), Q=conv(v^2); u=x+y, v=x-y.
    // SSIM needs only mu1^2+mu2^2, mu1*mu2, conv(x^2)+conv(y^2), conv(xy) —
    // all recoverable from these 4 (saves a 5th convolution + 11 history regs).
    DECL_HIST(A); DECL_HIST(B); DECL_HIST(P); DECL_HIST(Q);

    float lsum = 0.f;

#pragma unroll 2
    for (int t = r0 - 5; t <= r0 + RSTRIP + 4; ++t, rp1 += WW, rp2 += WW) {
        SHIFT_HIST(A); SHIFT_HIST(B); SHIFT_HIST(P); SHIFT_HIST(Q);

        float nA = 0.f, nB = 0.f, nP = 0.f, nQ = 0.f;
        if ((unsigned)t < (unsigned)HH) {            // uniform; rows outside are zero-pad
            float X0,X1,X2,X3,X4,X5,X6,X7,X8,X9,X10;
            float Y0,Y1,Y2,Y3,Y4,Y5,Y6,Y7,Y8,Y9,Y10;
            if (!edge) {
                F4 xa, xb, xc, ya, yb, yc;
                __builtin_memcpy(&xa, rp1 - 5, 16);
                __builtin_memcpy(&xb, rp1 - 1, 16);
                __builtin_memcpy(&xc, rp1 + 3, 16);
                __builtin_memcpy(&ya, rp2 - 5, 16);
                __builtin_memcpy(&yb, rp2 - 1, 16);
                __builtin_memcpy(&yc, rp2 + 3, 16);
                X0=xa.s0; X1=xa.s1; X2=xa.s2; X3=xa.s3;
                X4=xb.s0; X5=xb.s1; X6=xb.s2; X7=xb.s3;
                X8=xc.s0; X9=xc.s1; X10=xc.s2;
                Y0=ya.s0; Y1=ya.s1; Y2=ya.s2; Y3=ya.s3;
                Y4=yb.s0; Y5=yb.s1; Y6=yb.s2; Y7=yb.s3;
                Y8=yc.s0; Y9=yc.s1; Y10=yc.s2;
            } else {
#define EDGE_TAP(K) { int cc = c + (K) - 5; bool ok = (unsigned)cc < (unsigned)WW; \
                      X##K = ok ? rp1[(K) - 5] : 0.f; Y##K = ok ? rp2[(K) - 5] : 0.f; }
                EDGE_TAP(0) EDGE_TAP(1) EDGE_TAP(2) EDGE_TAP(3) EDGE_TAP(4)
                EDGE_TAP(5) EDGE_TAP(6) EDGE_TAP(7) EDGE_TAP(8) EDGE_TAP(9) EDGE_TAP(10)
#undef EDGE_TAP
            }
            const float U0=X0+Y0, V0=X0-Y0;
            const float U1=X1+Y1, V1=X1-Y1;
            const float U2=X2+Y2, V2=X2-Y2;
            const float U3=X3+Y3, V3=X3-Y3;
            const float U4=X4+Y4, V4=X4-Y4;
            const float U5=X5+Y5, V5=X5-Y5;
            const float U6=X6+Y6, V6=X6-Y6;
            const float U7=X7+Y7, V7=X7-Y7;
            const float U8=X8+Y8, V8=X8-Y8;
            const float U9=X9+Y9, V9=X9-Y9;
            const float U10=X10+Y10, V10=X10-Y10;

            nA = G0*U5;        nB = G0*V5;
            nP = G0*(U5*U5);   nQ = G0*(V5*V5);
            nA = fmaf(G1, U4+U6,  nA); nP = fmaf(G1, fmaf(U4,U4,U6*U6),   nP);
            nB = fmaf(G1, V4+V6,  nB); nQ = fmaf(G1, fmaf(V4,V4,V6*V6),   nQ);
            nA = fmaf(G2, U3+U7,  nA); nP = fmaf(G2, fmaf(U3,U3,U7*U7),   nP);
            nB = fmaf(G2, V3+V7,  nB); nQ = fmaf(G2, fmaf(V3,V3,V7*V7),   nQ);
            nA = fmaf(G3, U2+U8,  nA); nP = fmaf(G3, fmaf(U2,U2,U8*U8),   nP);
            nB = fmaf(G3, V2+V8,  nB); nQ = fmaf(G3, fmaf(V2,V2,V8*V8),   nQ);
            nA = fmaf(G4, U1+U9,  nA); nP = fmaf(G4, fmaf(U1,U1,U9*U9),   nP);
            nB = fmaf(G4, V1+V9,  nB); nQ = fmaf(G4, fmaf(V1,V1,V9*V9),   nQ);
            nA = fmaf(G5, U0+U10, nA); nP = fmaf(G5, fmaf(U0,U0,U10*U10), nP);
            nB = fmaf(G5, V0+V10, nB); nQ = fmaf(G5, fmaf(V0,V0,V10*V10), nQ);
        }
        A10 = nA; B10 = nB; P10 = nP; Q10 = nQ;

        const int s = t - 5 - r0;                    // output row within strip
        if ((unsigned)s < (unsigned)RSTRIP) {        // uniform; first 10 iters warm up
            const float mu_u = VCONV(A);
            const float mu_v = VCONV(B);
            const float cu2  = VCONV(P);
            const float cv2  = VCONV(Q);
            const float a = mu_u * mu_u;
            const float b = mu_v * mu_v;
            const float musq = 0.5f  * (a + b);      // mu1^2 + mu2^2
            const float mu12 = 0.25f * (a - b);      // mu1 * mu2
            const float csq  = 0.5f  * (cu2 + cv2);  // conv(x^2) + conv(y^2)
            const float cxy  = 0.25f * (cu2 - cv2);  // conv(x*y)
            const float ssum = csq - musq;           // sigma1^2 + sigma2^2
            const float s12  = cxy - mu12;           // sigma12
            const float num = fmaf(2.f, mu12, C1F) * fmaf(2.f, s12, C2F);
            const float den = (musq + C1F) * (ssum + C2F);
            lsum += num * __builtin_amdgcn_rcpf(den);
        }
    }

    // reduction: wave shfl -> LDS -> one atomic per block
#pragma unroll
    for (int off = 32; off > 0; off >>= 1)
        lsum += __shfl_down(lsum, off, 64);
    __shared__ float ws4[4];
    const int lane = threadIdx.x & 63;
    const int wv   = threadIdx.x >> 6;
    if (lane == 0) ws4[wv] = lsum;
    __syncthreads();
    if (threadIdx.x == 0)
        atomicAdd(acc, ws4[0] + ws4[1] + ws4[2] + ws4[3]);
}

__global__ void ssim_zero(float* acc) { acc[0] = 0.f; }

__global__ void ssim_finalize(const float* __restrict__ acc, float* __restrict__ out) {
    out[0] = 1.f - acc[0] * (1.f / NPIX);
}

extern "C" void kernel_launch(void* const* d_in, const int* in_sizes, int n_in,
                              void* d_out, int out_size, void* d_ws, size_t ws_size,
                              hipStream_t stream) {
    const float* img1 = (const float*)d_in[0];
    const float* img2 = (const float*)d_in[1];
    float* out = (float*)d_out;
    float* acc = (float*)d_ws;

    ssim_zero<<<1, 1, 0, stream>>>(acc);
    dim3 grid(WW / 256, HH / RSTRIP, PLANES);  // (2, 4, 96) = 768 blocks = 3/CU
    ssim_main<<<grid, 256, 0, stream>>>(img1, img2, acc);
    ssim_finalize<<<1, 1, 0, stream>>>(acc, out);
}